// Round 19
// baseline (542.166 us; speedup 1.0000x reference)
//
#include <hip/hip_runtime.h>
#include <stdint.h>

#define N_NODES 50000
#define D_MODEL 768
#define N_EDGES 100000
#define BM 128
#define NKT 24                 /* 768/32 */
#define MBLOCKS 391            /* ceil(50000/128) */
#define M_PAD (MBLOCKS * BM)   /* 50048 */
#define NCB 6                  /* 768/128 */
#define TILE_BYTES 8192        /* 128*32*2 */
#define TILE_ELEMS 4096
#define NWG (MBLOCKS * NCB)    /* 2346 */
#define GROWS0 16              /* gather rows/block (LDS-staged) */

typedef unsigned short ushort_t;
typedef __bf16 bf16x8 __attribute__((ext_vector_type(8)));
typedef float f32x4 __attribute__((ext_vector_type(4)));

__device__ __forceinline__ unsigned short f2bf(float f) {
  union { float f; unsigned u; } v; v.f = f;
  unsigned r = v.u + 0x7fffu + ((v.u >> 16) & 1u);
  return (unsigned short)(r >> 16);
}

__device__ __forceinline__ uint2 pack4(f32x4 v) {
  uint2 p;
  p.x = (unsigned)f2bf(v[0]) | ((unsigned)f2bf(v[1]) << 16);
  p.y = (unsigned)f2bf(v[2]) | ((unsigned)f2bf(v[3]) << 16);
  return p;
}

__device__ __forceinline__ f32x4 unp4(uint2 p) {
  union { unsigned u; float f; } c;
  f32x4 v;
  c.u = p.x << 16;          v[0] = c.f;
  c.u = p.x & 0xffff0000u;  v[1] = c.f;
  c.u = p.y << 16;          v[2] = c.f;
  c.u = p.y & 0xffff0000u;  v[3] = c.f;
  return v;
}

__device__ __forceinline__ void gload_lds16(const void* g, void* l) {
  __builtin_amdgcn_global_load_lds(
      (const __attribute__((address_space(1))) unsigned int*)g,
      (__attribute__((address_space(3))) unsigned int*)l, 16, 0, 0);
}

__device__ __forceinline__ int eidx(const unsigned* e, int logical, int is64) {
  return is64 ? (int)e[2 * logical] : (int)e[logical];
}

// ---- init: zero counts + colsum; block 0 also does edge-dtype detect ----
__global__ void k_init(const unsigned* __restrict__ e, int* counts, float* colsum,
                       int* eflag) {
  int i = blockIdx.x * 256 + threadIdx.x;
  if (i < N_NODES) counts[i] = 0;
  if (i < D_MODEL) colsum[i] = 0.0f;
  if (i == 0) {
    int is64 = 1;
    for (int k = 0; k < 64; ++k)
      if (e[2 * k + 1] != 0u) { is64 = 0; break; }
    *eflag = is64;
  }
}

__global__ void k_count(const unsigned* __restrict__ e, const int* __restrict__ eflag,
                        int* counts) {
  int i = blockIdx.x * 256 + threadIdx.x;
  if (i >= N_EDGES) return;
  int is64 = *eflag;
  int d = eidx(e, N_EDGES + i, is64);
  atomicAdd(&counts[d], 1);
}

// ---- CSR build: 3-phase exclusive scan of counts -> rowptr, then fill ----
__global__ void k_scan1(const int* __restrict__ counts, int* rowptr, int* bsum,
                        float* dinv) {
  __shared__ int sm[256];
  int b = blockIdx.x, t = threadIdx.x;
  int i = b * 256 + t;
  int v = (i < N_NODES) ? counts[i] : 0;
  if (i < N_NODES) dinv[i] = rsqrtf((float)(v + 1));  // deg = 1 + indeg
  sm[t] = v;
  __syncthreads();
#pragma unroll
  for (int off = 1; off < 256; off <<= 1) {
    int x = (t >= off) ? sm[t - off] : 0;
    __syncthreads();
    sm[t] += x;
    __syncthreads();
  }
  if (i < N_NODES) rowptr[i] = sm[t] - v;   // exclusive
  if (t == 255) bsum[b] = sm[255];
}

__global__ void k_scan2(int* bsum, int* boff) {
  __shared__ int sm[256];
  int t = threadIdx.x;
  int v = (t < 196) ? bsum[t] : 0;
  sm[t] = v;
  __syncthreads();
#pragma unroll
  for (int off = 1; off < 256; off <<= 1) {
    int x = (t >= off) ? sm[t - off] : 0;
    __syncthreads();
    sm[t] += x;
    __syncthreads();
  }
  boff[t] = sm[t] - v;  // exclusive
}

__global__ void k_scan3(int* rowptr, const int* __restrict__ boff, int* counts) {
  int b = blockIdx.x, t = threadIdx.x;
  int i = b * 256 + t;
  if (i < N_NODES) {
    rowptr[i] += boff[b];
    counts[i] = 0;       // reuse as fill cursor
  }
  if (i == 0) rowptr[N_NODES] = N_EDGES;
}

__global__ void k_fill(const unsigned* __restrict__ e, const int* __restrict__ eflag,
                       const int* __restrict__ rowptr, int* counts, int* csr) {
  int i = blockIdx.x * 256 + threadIdx.x;
  if (i >= N_EDGES) return;
  int is64 = *eflag;
  int s = eidx(e, i, is64);
  int d = eidx(e, N_EDGES + i, is64);
  int pos = atomicAdd(&counts[d], 1);
  csr[rowptr[d] + pos] = s;
}

// ---- pack all 3 W (f32 [768][768] row-major -> bf16 fragment-major tiles) ----
__global__ void k_pack_w3(const float* __restrict__ W1, const float* __restrict__ W2,
                          const float* __restrict__ W3, ushort_t* __restrict__ pwbase) {
  int which = blockIdx.x / 288;
  int u = (blockIdx.x % 288) * 256 + threadIdx.x;   // 73728 units per W
  if (u >= 6 * 24 * 8 * 64) return;
  const float* W = which == 0 ? W1 : (which == 1 ? W2 : W3);
  ushort_t* pw = pwbase + (size_t)which * D_MODEL * D_MODEL;
  int c    = u & 15;
  int g    = (u >> 4) & 3;
  int cb16 = (u >> 6) & 7;
  int kt   = (u >> 9) % NKT;
  int cb   = u / (512 * NKT);
  int col  = cb * 128 + cb16 * 16 + c;
  ushort_t o[8];
#pragma unroll
  for (int j = 0; j < 8; ++j) {
    int k = kt * 32 + g * 4 + (j & 3) + 16 * (j >> 2);
    o[j] = f2bf(W[(size_t)k * D_MODEL + col]);
  }
  uint2 w0, w1;
  w0.x = (unsigned)o[0] | ((unsigned)o[1] << 16);
  w0.y = (unsigned)o[2] | ((unsigned)o[3] << 16);
  w1.x = (unsigned)o[4] | ((unsigned)o[5] << 16);
  w1.y = (unsigned)o[6] | ((unsigned)o[7] << 16);
  uint2* dst = (uint2*)(pw + (size_t)u * 8);
  dst[0] = w0; dst[1] = w1;
}

// ---- gather_x (layer 1): pagg[r] = dinv[r]*(dinv[r]*x[r] + sum_in dinv[s]*x[s])
//   4 rows per wave concurrently: 4 independent csr chains in flight. ----
#define XROW_INIT(D)                                                              \
  int i##D = w * 4 + D;                                                           \
  int rr##D = rbase + i##D;                                                       \
  float dr##D = dinv[rr##D];                                                      \
  const f32x4* rp##D = (const f32x4*)(x + (size_t)rr##D * D_MODEL);               \
  f32x4 a##D##0 = rp##D[l] * dr##D, a##D##1 = rp##D[l + 64] * dr##D,              \
        a##D##2 = rp##D[l + 128] * dr##D;                                         \
  int j##D = srp[i##D], e##D = srp[i##D + 1];

#define XEDGE_STEP(D)                                                             \
  {                                                                               \
    bool act = j##D < e##D;                                                       \
    int s = act ? csr[j##D] : rr##D;                                              \
    float ds = dinv[s];                                                           \
    const f32x4* sp = (const f32x4*)(x + (size_t)s * D_MODEL);                    \
    f32x4 v0 = sp[l], v1 = sp[l + 64], v2 = sp[l + 128];                          \
    if (act) {                                                                    \
      a##D##0 += v0 * ds; a##D##1 += v1 * ds; a##D##2 += v2 * ds;                 \
      ++j##D;                                                                     \
    }                                                                             \
  }

#define IMG_WRITE(D, A0, A1, A2)                                                  \
  {                                                                               \
    int base = (i##D << 4) + qoffB;                                               \
    char* sp = sraw + (((kt0 * 1024) + base) ^ swz);                              \
    *(uint2*)(sp)         = pack4(A0);                                            \
    *(uint2*)(sp + 8192)  = pack4(A1);                                            \
    *(uint2*)(sp + 16384) = pack4(A2);                                            \
  }

__global__ __launch_bounds__(256) void k_gather_x(
    const int* __restrict__ rowptr, const int* __restrict__ csr,
    const float* __restrict__ dinv, const float* __restrict__ x,
    ushort_t* __restrict__ pagg) {
  __shared__ __align__(16) char sraw[GROWS0 * D_MODEL * 2];  // 24KB
  __shared__ int srp[GROWS0 + 1];
  int tid = threadIdx.x;
  int rbase = blockIdx.x * GROWS0;
  if (tid <= GROWS0) srp[tid] = rowptr[rbase + tid];
  __syncthreads();

  int w = tid >> 6, l = tid & 63;
  int kt0 = l >> 3, q = l & 7;
  int qoffB = (q & 3) * 256 + (q >> 2) * 8;
  int swz = kt0 << 4;

  XROW_INIT(0); XROW_INIT(1); XROW_INIT(2); XROW_INIT(3);

  while ((j0 < e0) | (j1 < e1) | (j2 < e2) | (j3 < e3)) {
    XEDGE_STEP(0); XEDGE_STEP(1); XEDGE_STEP(2); XEDGE_STEP(3);
  }

  a00 *= dr0; a01 *= dr0; a02 *= dr0;
  a10 *= dr1; a11 *= dr1; a12 *= dr1;
  a20 *= dr2; a21 *= dr2; a22 *= dr2;
  a30 *= dr3; a31 *= dr3; a32 *= dr3;

  IMG_WRITE(0, a00, a01, a02);
  IMG_WRITE(1, a10, a11, a12);
  IMG_WRITE(2, a20, a21, a22);
  IMG_WRITE(3, a30, a31, a32);

  __syncthreads();
  int bm = rbase >> 7, rb0 = (rbase >> 4) & 7;
  size_t tilebase = ((size_t)bm * NKT) * TILE_ELEMS + (size_t)rb0 * 512;
#pragma unroll
  for (int it = 0; it < 6; ++it) {
    int byte = (it * 256 + tid) * 16;
    int kt = byte >> 10;
    uint4 v = *(const uint4*)(sraw + (byte ^ ((kt & 7) << 4)));
    *(uint4*)((char*)(pagg + tilebase + (size_t)kt * TILE_ELEMS) + (byte & 1023)) = v;
  }
}

// ---- gather_agg (layers 2,3): pagg[r] = dinv[r]*(t[r] + sum_in t[s])
//   4 rows per wave concurrently. ----
#define TROW_INIT(D)                                                              \
  int i##D = w * 4 + D;                                                           \
  int rr##D = rbase + i##D;                                                       \
  const uint2* rp##D = (const uint2*)(t + (size_t)rr##D * D_MODEL);               \
  f32x4 a##D##0 = unp4(rp##D[l]), a##D##1 = unp4(rp##D[l + 64]),                  \
        a##D##2 = unp4(rp##D[l + 128]);                                           \
  int j##D = srp[i##D], e##D = srp[i##D + 1];

#define TEDGE_STEP(D)                                                             \
  {                                                                               \
    bool act = j##D < e##D;                                                       \
    int s = act ? csr[j##D] : rr##D;                                              \
    const uint2* sp = (const uint2*)(t + (size_t)s * D_MODEL);                    \
    uint2 v0 = sp[l], v1 = sp[l + 64], v2 = sp[l + 128];                          \
    if (act) {                                                                    \
      a##D##0 += unp4(v0); a##D##1 += unp4(v1); a##D##2 += unp4(v2);              \
      ++j##D;                                                                     \
    }                                                                             \
  }

__global__ __launch_bounds__(256) void k_gather_agg(
    const int* __restrict__ rowptr, const int* __restrict__ csr,
    const float* __restrict__ dinv, const ushort_t* __restrict__ t,
    ushort_t* __restrict__ pagg) {
  __shared__ __align__(16) char sraw[GROWS0 * D_MODEL * 2];  // 24KB
  __shared__ int srp[GROWS0 + 1];
  int tid = threadIdx.x;
  int rbase = blockIdx.x * GROWS0;
  if (tid <= GROWS0) srp[tid] = rowptr[rbase + tid];
  __syncthreads();

  int w = tid >> 6, l = tid & 63;
  int kt0 = l >> 3, q = l & 7;
  int qoffB = (q & 3) * 256 + (q >> 2) * 8;
  int swz = kt0 << 4;

  TROW_INIT(0); TROW_INIT(1); TROW_INIT(2); TROW_INIT(3);

  while ((j0 < e0) | (j1 < e1) | (j2 < e2) | (j3 < e3)) {
    TEDGE_STEP(0); TEDGE_STEP(1); TEDGE_STEP(2); TEDGE_STEP(3);
  }

  {
    float dA = dinv[rr0], dB = dinv[rr1], dC = dinv[rr2], dD = dinv[rr3];
    a00 *= dA; a01 *= dA; a02 *= dA;
    a10 *= dB; a11 *= dB; a12 *= dB;
    a20 *= dC; a21 *= dC; a22 *= dC;
    a30 *= dD; a31 *= dD; a32 *= dD;
  }

  IMG_WRITE(0, a00, a01, a02);
  IMG_WRITE(1, a10, a11, a12);
  IMG_WRITE(2, a20, a21, a22);
  IMG_WRITE(3, a30, a31, a32);

  __syncthreads();
  int bm = rbase >> 7, rb0 = (rbase >> 4) & 7;
  size_t tilebase = ((size_t)bm * NKT) * TILE_ELEMS + (size_t)rb0 * 512;
#pragma unroll
  for (int it = 0; it < 6; ++it) {
    int byte = (it * 256 + tid) * 16;
    int kt = byte >> 10;
    uint4 v = *(const uint4*)(sraw + (byte ^ ((kt & 7) << 4)));
    *(uint4*)((char*)(pagg + tilebase + (size_t)kt * TILE_ELEMS) + (byte & 1023)) = v;
  }
}

// ---- GEMM K-loop: 2-stage double-buffered, depth-1 prefetch, counted vmcnt,
//   setprio around MFMA cluster. Loads-only window in K-loop.
#define GEMM_STAGE(DSTBASE, KT)                                                   \
  {                                                                               \
    const char* ga_ = paT + (size_t)(KT) * TILE_BYTES;                            \
    const char* gb_ = pwT + (size_t)(KT) * TILE_BYTES;                            \
    char* nb_ = (DSTBASE);                                                        \
    gload_lds16(ga_ + (size_t)u * 1024 + (size_t)l * 16,       nb_ + u * 1024);   \
    gload_lds16(ga_ + (size_t)(u + 1) * 1024 + (size_t)l * 16, nb_ + (u + 1) * 1024); \
    gload_lds16(gb_ + (size_t)u * 1024 + (size_t)l * 16,       nb_ + 8192 + u * 1024); \
    gload_lds16(gb_ + (size_t)(u + 1) * 1024 + (size_t)l * 16, nb_ + 8192 + (u + 1) * 1024); \
  }

#define KBODY(B, KT, VM, STG)                                                     \
  {                                                                               \
    asm volatile("s_waitcnt vmcnt(" #VM ")" ::: "memory");                        \
    __builtin_amdgcn_s_barrier();                                                 \
    const char* base_ = smem + (B) * 16384;                                       \
    bf16x8 af[4], bfr[4];                                                         \
    _Pragma("unroll")                                                             \
    for (int m = 0; m < 4; ++m)                                                   \
      af[m] = *(const bf16x8*)&base_[(wm * 4 + m) * 1024 + g * 256 + r16 * 16];   \
    _Pragma("unroll")                                                             \
    for (int n = 0; n < 4; ++n)                                                   \
      bfr[n] = *(const bf16x8*)&base_[8192 + (wn * 4 + n) * 1024 + g * 256 + r16 * 16]; \
    asm volatile("s_waitcnt lgkmcnt(0)" ::: "memory");                            \
    __builtin_amdgcn_sched_barrier(0);                                            \
    __builtin_amdgcn_s_barrier();                                                 \
    if (STG) GEMM_STAGE(smem + (B) * 16384, (KT) + 2);                            \
    __builtin_amdgcn_s_setprio(1);                                                \
    _Pragma("unroll")                                                             \
    for (int m = 0; m < 4; ++m)                                                   \
      _Pragma("unroll")                                                           \
      for (int n = 0; n < 4; ++n)                                                 \
        acc[m][n] = __builtin_amdgcn_mfma_f32_16x16x32_bf16(af[m], bfr[n], acc[m][n], 0, 0, 0); \
    __builtin_amdgcn_s_setprio(0);                                                \
  }

// layers 1,2: t[row] = bf16( dinv[row] * relu( (agg@W)[row] + b ) ), row-major.
__global__ __launch_bounds__(256) void k_gemm12(
    const ushort_t* __restrict__ pa, const ushort_t* __restrict__ pw,
    const float* __restrict__ dinv, const float* __restrict__ bias,
    ushort_t* __restrict__ tout) {
  __shared__ __align__(16) char smem[2 * 16384];  // 2 buffers x {A 8KB, B 8KB}
  const int qq = NWG / 8, rm = NWG % 8;
  int orig = blockIdx.x;
  int xcd = orig & 7, idx = orig >> 3;
  int wgid = (xcd < rm ? xcd * (qq + 1) : rm * (qq + 1) + (xcd - rm) * qq) + idx;
  int bm = wgid / NCB, cb = wgid % NCB;

  int t = threadIdx.x, w = t >> 6, l = t & 63;
  int wm = w >> 1, wn = w & 1;
  int g = l >> 4, r16 = l & 15;
  int u = w * 2;

  // hoisted epilogue operands (retire before the first vmcnt wait)
  int colb = cb * 128 + wn * 64;
  float bn[4];
#pragma unroll
  for (int n = 0; n < 4; ++n) bn[n] = bias[colb + n * 16 + r16];
  float dv[4][4];
#pragma unroll
  for (int m = 0; m < 4; ++m)
#pragma unroll
    for (int reg = 0; reg < 4; ++reg)
      dv[m][reg] = dinv[bm * BM + wm * 64 + m * 16 + g * 4 + reg];  // buf padded

  f32x4 acc[4][4] = {};

  const char* paT = (const char*)pa + (size_t)bm * NKT * TILE_BYTES;
  const char* pwT = (const char*)pw + (size_t)cb * NKT * TILE_BYTES;

  GEMM_STAGE(smem, 0);
  GEMM_STAGE(smem + 16384, 1);

#pragma unroll 1
  for (int kt = 0; kt < 22; kt += 2) {
    KBODY(0, kt, 4, 1);
    KBODY(1, kt + 1, 4, 1);
  }
  KBODY(0, 22, 4, 0);
  KBODY(1, 23, 0, 0);

  // epilogue: stage bf16 in LDS [32][136] (buffer-0 region), uint4 stores
  ushort_t* stg = (ushort_t*)smem;
  const int SR = 136;   // 272B rows: 16B-aligned, 2-way-max bank aliasing
  for (int m = 0; m < 4; ++m) {
#pragma unroll
    for (int reg = 0; reg < 4; ++reg) {
      int lrow = wm * 16 + g * 4 + reg;
      float di = dv[m][reg];
#pragma unroll
      for (int n = 0; n < 4; ++n)
        stg[lrow * SR + wn * 64 + n * 16 + r16] =
            f2bf(di * fmaxf(acc[m][n][reg] + bn[n], 0.f));
    }
    __syncthreads();
#pragma unroll
    for (int it = 0; it < 2; ++it) {
      int lrow = it * 16 + (t >> 4);
      int row = bm * BM + (lrow >> 4) * 64 + m * 16 + (lrow & 15);
      if (row < N_NODES) {
        uint4 v = *(const uint4*)&stg[lrow * SR + (t & 15) * 8];
        *(uint4*)(tout + (size_t)row * D_MODEL + cb * 128 + (t & 15) * 8) = v;
      }
    }
    __syncthreads();
  }
}

// layer 3: hout[row] = relu((agg@W3)[row] + b3) + x[row] (f32) + colsum reduce.
__global__ __launch_bounds__(256) void k_gemm3(
    const ushort_t* __restrict__ pa, const ushort_t* __restrict__ pw,
    const float* __restrict__ bias, const float* __restrict__ x,
    float* __restrict__ hout, float* __restrict__ colsum) {
  __shared__ __align__(16) char smem[2 * 16384];  // dbuf; epilogue reuses region
  const int qq = NWG / 8, rm = NWG % 8;
  int orig = blockIdx.x;
  int xcd = orig & 7, idx = orig >> 3;
  int wgid = (xcd < rm ? xcd * (qq + 1) : rm * (qq + 1) + (xcd - rm) * qq) + idx;
  int bm = wgid / NCB, cb = wgid % NCB;

  int t = threadIdx.x, w = t >> 6, l = t & 63;
  int wm = w >> 1, wn = w & 1;
  int g = l >> 4, r16 = l & 15;
  int u = w * 2;

  int colb = cb * 128 + wn * 64;
  float bn[4];
#pragma unroll
  for (int n = 0; n < 4; ++n) bn[n] = bias[colb + n * 16 + r16];

  f32x4 acc[4][4] = {};

  const char* paT = (const char*)pa + (size_t)bm * NKT * TILE_BYTES;
  const char* pwT = (const char*)pw + (size_t)cb * NKT * TILE_BYTES;

  GEMM_STAGE(smem, 0);
  GEMM_STAGE(smem + 16384, 1);

#pragma unroll 1
  for (int kt = 0; kt < 22; kt += 2) {
    KBODY(0, kt, 4, 1);
    KBODY(1, kt + 1, 4, 1);
  }
  KBODY(0, 22, 4, 0);
  KBODY(1, 23, 0, 0);

  // epilogue: stage relu(acc+b) f32 in LDS [32][132] (first 16.9KB);
  // scol at +17408; vectorized x-load + h-store + colsum.
  float* stage = (float*)smem;
  float* scol = (float*)(smem + 17408);
  const int SROW = 132;  // 528B rows: 16B-aligned, 2-way-max bank aliasing
  if (t < 128) scol[t] = 0.f;
  f32x4 cp = {0.f, 0.f, 0.f, 0.f};
  int jc = (t & 31) * 4;           // 4 consecutive cols per thread (fixed)
  int rsub = t >> 5;               // 0..7
  int colb0 = cb * 128;
  __syncthreads();
  for (int m = 0; m < 4; ++m) {
#pragma unroll
    for (int reg = 0; reg < 4; ++reg) {
      int lrow = wm * 16 + g * 4 + reg;
#pragma unroll
      for (int n = 0; n < 4; ++n)
        stage[lrow * SROW + wn * 64 + n * 16 + r16] = fmaxf(acc[m][n][reg] + bn[n], 0.f);
    }
    __syncthreads();
#pragma unroll
    for (int it = 0; it < 4; ++it) {
      int lrow = it * 8 + rsub;
      int row = bm * BM + (lrow >> 4) * 64 + m * 16 + (lrow & 15);
      if (row < N_NODES) {
        f32x4 v = *(const f32x4*)&stage[lrow * SROW + jc];
        f32x4 xv = *(const f32x4*)(x + (size_t)row * D_MODEL + colb0 + jc);
        v += xv;
        *(f32x4*)(hout + (size_t)row * D_MODEL + colb0 + jc) = v;
        cp += v;
      }
    }
    __syncthreads();
  }
#pragma unroll
  for (int c = 0; c < 4; ++c) atomicAdd(&scol[jc + c], cp[c]);
  __syncthreads();
  if (t < 128) atomicAdd(&colsum[cb * 128 + t], scol[t]);
}

// ---- final: out = (colsum/N) @ Wl + bl ----
__global__ void k_final(const float* __restrict__ colsum, const float* __restrict__ Wl,
                        const float* __restrict__ bl, float* __restrict__ out) {
  int j = blockIdx.x * 128 + threadIdx.x;
  if (j >= D_MODEL) return;
  float s = 0.f;
  for (int k = 0; k < D_MODEL; ++k)
    s += colsum[k] * Wl[(size_t)k * D_MODEL + j];
  out[j] = s * (1.0f / (float)N_NODES) + bl[j];
}

extern "C" void kernel_launch(void* const* d_in, const int* in_sizes, int n_in,
                              void* d_out, int out_size, void* d_ws, size_t ws_size,
                              hipStream_t stream) {
  const float* x      = (const float*)d_in[0];
  const unsigned* edg = (const unsigned*)d_in[1];
  const float* W1 = (const float*)d_in[2];
  const float* b1 = (const float*)d_in[3];
  const float* W2 = (const float*)d_in[4];
  const float* b2 = (const float*)d_in[5];
  const float* W3 = (const float*)d_in[6];
  const float* b3 = (const float*)d_in[7];
  const float* Wl = (const float*)d_in[8];
  const float* bl = (const float*)d_in[9];

  float* hout = (float*)d_out;
  float* oout = hout + (size_t)N_NODES * D_MODEL;

  char* ws = (char*)d_ws;
  size_t off = 0;
  ushort_t* t = (ushort_t*)(ws + off);   off += (size_t)N_NODES * D_MODEL * 2;  // 76.8 MB
  ushort_t* pagg = (ushort_t*)(ws + off); off += (size_t)M_PAD * D_MODEL * 2;   // 76.9 MB
  ushort_t* pw0 = (ushort_t*)(ws + off); off += (size_t)D_MODEL * D_MODEL * 2;
  ushort_t* pw1 = (ushort_t*)(ws + off); off += (size_t)D_MODEL * D_MODEL * 2;
  ushort_t* pw2 = (ushort_t*)(ws + off); off += (size_t)D_MODEL * D_MODEL * 2;
  float* dinv = (float*)(ws + off);      off += 50176 * 4;
  int* counts = (int*)(ws + off);        off += 50176 * 4;
  int* rowptr = (int*)(ws + off);        off += 50304 * 4;
  int* csr = (int*)(ws + off);           off += (size_t)N_EDGES * 4;
  int* bsum = (int*)(ws + off);          off += 256 * 4;
  int* boff = (int*)(ws + off);          off += 256 * 4;
  float* colsum = (float*)(ws + off);    off += 1024;
  int* eflag = (int*)(ws + off);         off += 256;

  // setup (edge structure is static across layers)
  k_init<<<196, 256, 0, stream>>>(edg, counts, colsum, eflag);
  k_count<<<391, 256, 0, stream>>>(edg, eflag, counts);
  k_scan1<<<196, 256, 0, stream>>>(counts, rowptr, bsum, dinv);
  k_scan2<<<1, 256, 0, stream>>>(bsum, boff);
  k_scan3<<<196, 256, 0, stream>>>(rowptr, boff, counts);
  k_fill<<<391, 256, 0, stream>>>(edg, eflag, rowptr, counts, csr);
  k_pack_w3<<<864, 256, 0, stream>>>(W1, W2, W3, pw0);

  const int NGB = N_NODES / GROWS0;  // 3125
  // layer 1 (gather fused with dinv*x scaling)
  k_gather_x<<<NGB, 256, 0, stream>>>(rowptr, csr, dinv, x, pagg);
  k_gemm12<<<NWG, 256, 0, stream>>>(pagg, pw0, dinv, b1, t);
  // layer 2
  k_gather_agg<<<NGB, 256, 0, stream>>>(rowptr, csr, dinv, t, pagg);
  k_gemm12<<<NWG, 256, 0, stream>>>(pagg, pw1, dinv, b2, t);
  // layer 3 (epilogue fuses bias+relu+residual+colsum, f32 out)
  k_gather_agg<<<NGB, 256, 0, stream>>>(rowptr, csr, dinv, t, pagg);
  k_gemm3<<<NWG, 256, 0, stream>>>(pagg, pw2, b3, x, hout, colsum);

  k_final<<<6, 128, 0, stream>>>(colsum, Wl, bl, oout);
}

// Round 20
// 530.404 us; speedup vs baseline: 1.0222x; 1.0222x over previous
//
#include <hip/hip_runtime.h>
#include <stdint.h>

#define N_NODES 50000
#define D_MODEL 768
#define N_EDGES 100000
#define BM 128
#define NKT 24                 /* 768/32 */
#define MBLOCKS 391            /* ceil(50000/128) */
#define M_PAD (MBLOCKS * BM)   /* 50048 */
#define NCB 6                  /* 768/128 */
#define TILE_BYTES 8192        /* 128*32*2 */
#define TILE_ELEMS 4096
#define NWG (MBLOCKS * NCB)    /* 2346 */
#define GROWS0 16              /* gather rows/block (LDS-staged) */

typedef unsigned short ushort_t;
typedef __bf16 bf16x8 __attribute__((ext_vector_type(8)));
typedef float f32x4 __attribute__((ext_vector_type(4)));

__device__ __forceinline__ unsigned short f2bf(float f) {
  union { float f; unsigned u; } v; v.f = f;
  unsigned r = v.u + 0x7fffu + ((v.u >> 16) & 1u);
  return (unsigned short)(r >> 16);
}

__device__ __forceinline__ uint2 pack4(f32x4 v) {
  uint2 p;
  p.x = (unsigned)f2bf(v[0]) | ((unsigned)f2bf(v[1]) << 16);
  p.y = (unsigned)f2bf(v[2]) | ((unsigned)f2bf(v[3]) << 16);
  return p;
}

__device__ __forceinline__ f32x4 unp4(uint2 p) {
  union { unsigned u; float f; } c;
  f32x4 v;
  c.u = p.x << 16;          v[0] = c.f;
  c.u = p.x & 0xffff0000u;  v[1] = c.f;
  c.u = p.y << 16;          v[2] = c.f;
  c.u = p.y & 0xffff0000u;  v[3] = c.f;
  return v;
}

__device__ __forceinline__ void gload_lds16(const void* g, void* l) {
  __builtin_amdgcn_global_load_lds(
      (const __attribute__((address_space(1))) unsigned int*)g,
      (__attribute__((address_space(3))) unsigned int*)l, 16, 0, 0);
}

__device__ __forceinline__ int eidx(const unsigned* e, int logical, int is64) {
  return is64 ? (int)e[2 * logical] : (int)e[logical];
}

// ---- init: zero counts + colsum; block 0 also does edge-dtype detect ----
__global__ void k_init(const unsigned* __restrict__ e, int* counts, float* colsum,
                       int* eflag) {
  int i = blockIdx.x * 256 + threadIdx.x;
  if (i < N_NODES) counts[i] = 0;
  if (i < D_MODEL) colsum[i] = 0.0f;
  if (i == 0) {
    int is64 = 1;
    for (int k = 0; k < 64; ++k)
      if (e[2 * k + 1] != 0u) { is64 = 0; break; }
    *eflag = is64;
  }
}

__global__ void k_count(const unsigned* __restrict__ e, const int* __restrict__ eflag,
                        int* counts) {
  int i = blockIdx.x * 256 + threadIdx.x;
  if (i >= N_EDGES) return;
  int is64 = *eflag;
  int d = eidx(e, N_EDGES + i, is64);
  atomicAdd(&counts[d], 1);
}

// ---- CSR build: 3-phase exclusive scan of counts -> rowptr, then fill ----
__global__ void k_scan1(const int* __restrict__ counts, int* rowptr, int* bsum,
                        float* dinv) {
  __shared__ int sm[256];
  int b = blockIdx.x, t = threadIdx.x;
  int i = b * 256 + t;
  int v = (i < N_NODES) ? counts[i] : 0;
  if (i < N_NODES) dinv[i] = rsqrtf((float)(v + 1));  // deg = 1 + indeg
  sm[t] = v;
  __syncthreads();
#pragma unroll
  for (int off = 1; off < 256; off <<= 1) {
    int x = (t >= off) ? sm[t - off] : 0;
    __syncthreads();
    sm[t] += x;
    __syncthreads();
  }
  if (i < N_NODES) rowptr[i] = sm[t] - v;   // exclusive
  if (t == 255) bsum[b] = sm[255];
}

__global__ void k_scan2(int* bsum, int* boff) {
  __shared__ int sm[256];
  int t = threadIdx.x;
  int v = (t < 196) ? bsum[t] : 0;
  sm[t] = v;
  __syncthreads();
#pragma unroll
  for (int off = 1; off < 256; off <<= 1) {
    int x = (t >= off) ? sm[t - off] : 0;
    __syncthreads();
    sm[t] += x;
    __syncthreads();
  }
  boff[t] = sm[t] - v;  // exclusive
}

__global__ void k_scan3(int* rowptr, const int* __restrict__ boff, int* counts) {
  int b = blockIdx.x, t = threadIdx.x;
  int i = b * 256 + t;
  if (i < N_NODES) {
    rowptr[i] += boff[b];
    counts[i] = 0;       // reuse as fill cursor
  }
  if (i == 0) rowptr[N_NODES] = N_EDGES;
}

__global__ void k_fill(const unsigned* __restrict__ e, const int* __restrict__ eflag,
                       const int* __restrict__ rowptr, int* counts, int* csr) {
  int i = blockIdx.x * 256 + threadIdx.x;
  if (i >= N_EDGES) return;
  int is64 = *eflag;
  int s = eidx(e, i, is64);
  int d = eidx(e, N_EDGES + i, is64);
  int pos = atomicAdd(&counts[d], 1);
  csr[rowptr[d] + pos] = s;
}

// ---- pack all 3 W (f32 [768][768] row-major -> bf16 fragment-major tiles) ----
__global__ void k_pack_w3(const float* __restrict__ W1, const float* __restrict__ W2,
                          const float* __restrict__ W3, ushort_t* __restrict__ pwbase) {
  int which = blockIdx.x / 288;
  int u = (blockIdx.x % 288) * 256 + threadIdx.x;   // 73728 units per W
  if (u >= 6 * 24 * 8 * 64) return;
  const float* W = which == 0 ? W1 : (which == 1 ? W2 : W3);
  ushort_t* pw = pwbase + (size_t)which * D_MODEL * D_MODEL;
  int c    = u & 15;
  int g    = (u >> 4) & 3;
  int cb16 = (u >> 6) & 7;
  int kt   = (u >> 9) % NKT;
  int cb   = u / (512 * NKT);
  int col  = cb * 128 + cb16 * 16 + c;
  ushort_t o[8];
#pragma unroll
  for (int j = 0; j < 8; ++j) {
    int k = kt * 32 + g * 4 + (j & 3) + 16 * (j >> 2);
    o[j] = f2bf(W[(size_t)k * D_MODEL + col]);
  }
  uint2 w0, w1;
  w0.x = (unsigned)o[0] | ((unsigned)o[1] << 16);
  w0.y = (unsigned)o[2] | ((unsigned)o[3] << 16);
  w1.x = (unsigned)o[4] | ((unsigned)o[5] << 16);
  w1.y = (unsigned)o[6] | ((unsigned)o[7] << 16);
  uint2* dst = (uint2*)(pw + (size_t)u * 8);
  dst[0] = w0; dst[1] = w1;
}

// ---- gather_x (layer 1): pagg[r] = dinv[r]*(dinv[r]*x[r] + sum_in dinv[s]*x[s]) ----
__global__ __launch_bounds__(256) void k_gather_x(
    const int* __restrict__ rowptr, const int* __restrict__ csr,
    const float* __restrict__ dinv, const float* __restrict__ x,
    ushort_t* __restrict__ pagg) {
  __shared__ __align__(16) char sraw[GROWS0 * D_MODEL * 2];  // 24KB
  __shared__ int srp[GROWS0 + 1];
  int tid = threadIdx.x;
  int r0 = blockIdx.x * GROWS0;
  if (tid <= GROWS0) srp[tid] = rowptr[r0 + tid];
  __syncthreads();

  int w = tid >> 6, l = tid & 63;
  int kt0 = l >> 3, q = l & 7;
  int qoffB = (q & 3) * 256 + (q >> 2) * 8;
  int swz = kt0 << 4;

  for (int p = w; p < GROWS0 / 2; p += 4) {     // 2 rows per wave concurrently
    int iA = p, iB = p + GROWS0 / 2;
    int rA = r0 + iA, rB = r0 + iB;
    float dA = dinv[rA], dB = dinv[rB];
    const f32x4* rpA = (const f32x4*)(x + (size_t)rA * D_MODEL);
    const f32x4* rpB = (const f32x4*)(x + (size_t)rB * D_MODEL);
    f32x4 a0 = rpA[l] * dA, a1 = rpA[l + 64] * dA, a2 = rpA[l + 128] * dA;
    f32x4 c0 = rpB[l] * dB, c1 = rpB[l + 64] * dB, c2 = rpB[l + 128] * dB;
    int jA = srp[iA], eA = srp[iA + 1];
    int jB = srp[iB], eB = srp[iB + 1];
    while (jA < eA && jB < eB) {
      int sA = csr[jA++], sB = csr[jB++];
      float dsA = dinv[sA], dsB = dinv[sB];
      const f32x4* pA = (const f32x4*)(x + (size_t)sA * D_MODEL);
      const f32x4* pB = (const f32x4*)(x + (size_t)sB * D_MODEL);
      f32x4 x0 = pA[l], x1 = pA[l + 64], x2 = pA[l + 128];
      f32x4 y0 = pB[l], y1 = pB[l + 64], y2 = pB[l + 128];
      a0 += x0 * dsA; a1 += x1 * dsA; a2 += x2 * dsA;
      c0 += y0 * dsB; c1 += y1 * dsB; c2 += y2 * dsB;
    }
    while (jA < eA) {
      int sA = csr[jA++];
      float dsA = dinv[sA];
      const f32x4* pA = (const f32x4*)(x + (size_t)sA * D_MODEL);
      a0 += pA[l] * dsA; a1 += pA[l + 64] * dsA; a2 += pA[l + 128] * dsA;
    }
    while (jB < eB) {
      int sB = csr[jB++];
      float dsB = dinv[sB];
      const f32x4* pB = (const f32x4*)(x + (size_t)sB * D_MODEL);
      c0 += pB[l] * dsB; c1 += pB[l + 64] * dsB; c2 += pB[l + 128] * dsB;
    }
    a0 *= dA; a1 *= dA; a2 *= dA;
    c0 *= dB; c1 *= dB; c2 *= dB;
    int baseA = (iA << 4) + qoffB, baseB = (iB << 4) + qoffB;
    char* sA0 = sraw + (((kt0 * 1024) + baseA) ^ swz);
    char* sB0 = sraw + (((kt0 * 1024) + baseB) ^ swz);
    *(uint2*)(sA0)         = pack4(a0);
    *(uint2*)(sA0 + 8192)  = pack4(a1);
    *(uint2*)(sA0 + 16384) = pack4(a2);
    *(uint2*)(sB0)         = pack4(c0);
    *(uint2*)(sB0 + 8192)  = pack4(c1);
    *(uint2*)(sB0 + 16384) = pack4(c2);
  }

  __syncthreads();
  int bm = r0 >> 7, rb0 = (r0 >> 4) & 7;
  size_t tilebase = ((size_t)bm * NKT) * TILE_ELEMS + (size_t)rb0 * 512;
#pragma unroll
  for (int it = 0; it < 6; ++it) {
    int byte = (it * 256 + tid) * 16;
    int kt = byte >> 10;
    uint4 v = *(const uint4*)(sraw + (byte ^ ((kt & 7) << 4)));
    *(uint4*)((char*)(pagg + tilebase + (size_t)kt * TILE_ELEMS) + (byte & 1023)) = v;
  }
}

// ---- gather_agg (layers 2,3): pagg[r] = dinv[r]*(t[r] + sum_in t[s]) ----
__global__ __launch_bounds__(256) void k_gather_agg(
    const int* __restrict__ rowptr, const int* __restrict__ csr,
    const float* __restrict__ dinv, const ushort_t* __restrict__ t,
    ushort_t* __restrict__ pagg) {
  __shared__ __align__(16) char sraw[GROWS0 * D_MODEL * 2];  // 24KB
  __shared__ int srp[GROWS0 + 1];
  int tid = threadIdx.x;
  int r0 = blockIdx.x * GROWS0;
  if (tid <= GROWS0) srp[tid] = rowptr[r0 + tid];
  __syncthreads();

  int w = tid >> 6, l = tid & 63;
  int kt0 = l >> 3, q = l & 7;
  int qoffB = (q & 3) * 256 + (q >> 2) * 8;
  int swz = kt0 << 4;

  for (int p = w; p < GROWS0 / 2; p += 4) {
    int iA = p, iB = p + GROWS0 / 2;
    int rA = r0 + iA, rB = r0 + iB;
    const uint2* rpA = (const uint2*)(t + (size_t)rA * D_MODEL);
    const uint2* rpB = (const uint2*)(t + (size_t)rB * D_MODEL);
    f32x4 a0 = unp4(rpA[l]), a1 = unp4(rpA[l + 64]), a2 = unp4(rpA[l + 128]);
    f32x4 c0 = unp4(rpB[l]), c1 = unp4(rpB[l + 64]), c2 = unp4(rpB[l + 128]);
    int jA = srp[iA], eA = srp[iA + 1];
    int jB = srp[iB], eB = srp[iB + 1];
    while (jA < eA && jB < eB) {
      int sA = csr[jA++], sB = csr[jB++];
      const uint2* pA = (const uint2*)(t + (size_t)sA * D_MODEL);
      const uint2* pB = (const uint2*)(t + (size_t)sB * D_MODEL);
      uint2 x0 = pA[l], x1 = pA[l + 64], x2 = pA[l + 128];
      uint2 y0 = pB[l], y1 = pB[l + 64], y2 = pB[l + 128];
      a0 += unp4(x0); a1 += unp4(x1); a2 += unp4(x2);
      c0 += unp4(y0); c1 += unp4(y1); c2 += unp4(y2);
    }
    while (jA < eA) {
      int sA = csr[jA++];
      const uint2* pA = (const uint2*)(t + (size_t)sA * D_MODEL);
      a0 += unp4(pA[l]); a1 += unp4(pA[l + 64]); a2 += unp4(pA[l + 128]);
    }
    while (jB < eB) {
      int sB = csr[jB++];
      const uint2* pB = (const uint2*)(t + (size_t)sB * D_MODEL);
      c0 += unp4(pB[l]); c1 += unp4(pB[l + 64]); c2 += unp4(pB[l + 128]);
    }
    float dA = dinv[rA], dB = dinv[rB];
    a0 *= dA; a1 *= dA; a2 *= dA;
    c0 *= dB; c1 *= dB; c2 *= dB;
    int baseA = (iA << 4) + qoffB, baseB = (iB << 4) + qoffB;
    char* sA0 = sraw + (((kt0 * 1024) + baseA) ^ swz);
    char* sB0 = sraw + (((kt0 * 1024) + baseB) ^ swz);
    *(uint2*)(sA0)         = pack4(a0);
    *(uint2*)(sA0 + 8192)  = pack4(a1);
    *(uint2*)(sA0 + 16384) = pack4(a2);
    *(uint2*)(sB0)         = pack4(c0);
    *(uint2*)(sB0 + 8192)  = pack4(c1);
    *(uint2*)(sB0 + 16384) = pack4(c2);
  }

  __syncthreads();
  int bm = r0 >> 7, rb0 = (r0 >> 4) & 7;
  size_t tilebase = ((size_t)bm * NKT) * TILE_ELEMS + (size_t)rb0 * 512;
#pragma unroll
  for (int it = 0; it < 6; ++it) {
    int byte = (it * 256 + tid) * 16;
    int kt = byte >> 10;
    uint4 v = *(const uint4*)(sraw + (byte ^ ((kt & 7) << 4)));
    *(uint4*)((char*)(pagg + tilebase + (size_t)kt * TILE_ELEMS) + (byte & 1023)) = v;
  }
}

// ---- GEMM K-loop: 2-stage double-buffered, depth-1 prefetch, counted vmcnt,
//   setprio around MFMA cluster. Loads-only window in K-loop.
#define GEMM_STAGE(DSTBASE, KT)                                                   \
  {                                                                               \
    const char* ga_ = paT + (size_t)(KT) * TILE_BYTES;                            \
    const char* gb_ = pwT + (size_t)(KT) * TILE_BYTES;                            \
    char* nb_ = (DSTBASE);                                                        \
    gload_lds16(ga_ + (size_t)u * 1024 + (size_t)l * 16,       nb_ + u * 1024);   \
    gload_lds16(ga_ + (size_t)(u + 1) * 1024 + (size_t)l * 16, nb_ + (u + 1) * 1024); \
    gload_lds16(gb_ + (size_t)u * 1024 + (size_t)l * 16,       nb_ + 8192 + u * 1024); \
    gload_lds16(gb_ + (size_t)(u + 1) * 1024 + (size_t)l * 16, nb_ + 8192 + (u + 1) * 1024); \
  }

#define KBODY(B, KT, VM, STG)                                                     \
  {                                                                               \
    asm volatile("s_waitcnt vmcnt(" #VM ")" ::: "memory");                        \
    __builtin_amdgcn_s_barrier();                                                 \
    const char* base_ = smem + (B) * 16384;                                       \
    bf16x8 af[4], bfr[4];                                                         \
    _Pragma("unroll")                                                             \
    for (int m = 0; m < 4; ++m)                                                   \
      af[m] = *(const bf16x8*)&base_[(wm * 4 + m) * 1024 + g * 256 + r16 * 16];   \
    _Pragma("unroll")                                                             \
    for (int n = 0; n < 4; ++n)                                                   \
      bfr[n] = *(const bf16x8*)&base_[8192 + (wn * 4 + n) * 1024 + g * 256 + r16 * 16]; \
    asm volatile("s_waitcnt lgkmcnt(0)" ::: "memory");                            \
    __builtin_amdgcn_sched_barrier(0);                                            \
    __builtin_amdgcn_s_barrier();                                                 \
    if (STG) GEMM_STAGE(smem + (B) * 16384, (KT) + 2);                            \
    __builtin_amdgcn_s_setprio(1);                                                \
    _Pragma("unroll")                                                             \
    for (int m = 0; m < 4; ++m)                                                   \
      _Pragma("unroll")                                                           \
      for (int n = 0; n < 4; ++n)                                                 \
        acc[m][n] = __builtin_amdgcn_mfma_f32_16x16x32_bf16(af[m], bfr[n], acc[m][n], 0, 0, 0); \
    __builtin_amdgcn_s_setprio(0);                                                \
  }

// layers 1,2: t[row] = bf16( dinv[row] * relu( (agg@W)[row] + b ) ), row-major.
__global__ __launch_bounds__(256) void k_gemm12(
    const ushort_t* __restrict__ pa, const ushort_t* __restrict__ pw,
    const float* __restrict__ dinv, const float* __restrict__ bias,
    ushort_t* __restrict__ tout) {
  __shared__ __align__(16) char smem[2 * 16384];  // 2 buffers x {A 8KB, B 8KB}
  const int qq = NWG / 8, rm = NWG % 8;
  int orig = blockIdx.x;
  int xcd = orig & 7, idx = orig >> 3;
  int wgid = (xcd < rm ? xcd * (qq + 1) : rm * (qq + 1) + (xcd - rm) * qq) + idx;
  int bm = wgid / NCB, cb = wgid % NCB;

  int t = threadIdx.x, w = t >> 6, l = t & 63;
  int wm = w >> 1, wn = w & 1;
  int g = l >> 4, r16 = l & 15;
  int u = w * 2;

  // hoisted epilogue operands (retire before the first vmcnt wait)
  int colb = cb * 128 + wn * 64;
  float bn[4];
#pragma unroll
  for (int n = 0; n < 4; ++n) bn[n] = bias[colb + n * 16 + r16];
  float dv[4][4];
#pragma unroll
  for (int m = 0; m < 4; ++m)
#pragma unroll
    for (int reg = 0; reg < 4; ++reg)
      dv[m][reg] = dinv[bm * BM + wm * 64 + m * 16 + g * 4 + reg];  // buf padded

  f32x4 acc[4][4] = {};

  const char* paT = (const char*)pa + (size_t)bm * NKT * TILE_BYTES;
  const char* pwT = (const char*)pw + (size_t)cb * NKT * TILE_BYTES;

  GEMM_STAGE(smem, 0);
  GEMM_STAGE(smem + 16384, 1);

#pragma unroll 1
  for (int kt = 0; kt < 22; kt += 2) {
    KBODY(0, kt, 4, 1);
    KBODY(1, kt + 1, 4, 1);
  }
  KBODY(0, 22, 4, 0);
  KBODY(1, 23, 0, 0);

  // epilogue: stage bf16 in LDS [32][136] (buffer-0 region), uint4 stores
  ushort_t* stg = (ushort_t*)smem;
  const int SR = 136;   // 272B rows: 16B-aligned, 2-way-max bank aliasing
  for (int m = 0; m < 4; ++m) {
#pragma unroll
    for (int reg = 0; reg < 4; ++reg) {
      int lrow = wm * 16 + g * 4 + reg;
      float di = dv[m][reg];
#pragma unroll
      for (int n = 0; n < 4; ++n)
        stg[lrow * SR + wn * 64 + n * 16 + r16] =
            f2bf(di * fmaxf(acc[m][n][reg] + bn[n], 0.f));
    }
    __syncthreads();
#pragma unroll
    for (int it = 0; it < 2; ++it) {
      int lrow = it * 16 + (t >> 4);
      int row = bm * BM + (lrow >> 4) * 64 + m * 16 + (lrow & 15);
      if (row < N_NODES) {
        uint4 v = *(const uint4*)&stg[lrow * SR + (t & 15) * 8];
        *(uint4*)(tout + (size_t)row * D_MODEL + cb * 128 + (t & 15) * 8) = v;
      }
    }
    __syncthreads();
  }
}

// layer 3: hout[row] = relu((agg@W3)[row] + b3) + x[row] (f32) + colsum reduce.
__global__ __launch_bounds__(256) void k_gemm3(
    const ushort_t* __restrict__ pa, const ushort_t* __restrict__ pw,
    const float* __restrict__ bias, const float* __restrict__ x,
    float* __restrict__ hout, float* __restrict__ colsum) {
  __shared__ __align__(16) char smem[2 * 16384];  // dbuf; epilogue reuses region
  const int qq = NWG / 8, rm = NWG % 8;
  int orig = blockIdx.x;
  int xcd = orig & 7, idx = orig >> 3;
  int wgid = (xcd < rm ? xcd * (qq + 1) : rm * (qq + 1) + (xcd - rm) * qq) + idx;
  int bm = wgid / NCB, cb = wgid % NCB;

  int t = threadIdx.x, w = t >> 6, l = t & 63;
  int wm = w >> 1, wn = w & 1;
  int g = l >> 4, r16 = l & 15;
  int u = w * 2;

  int colb = cb * 128 + wn * 64;
  float bn[4];
#pragma unroll
  for (int n = 0; n < 4; ++n) bn[n] = bias[colb + n * 16 + r16];

  f32x4 acc[4][4] = {};

  const char* paT = (const char*)pa + (size_t)bm * NKT * TILE_BYTES;
  const char* pwT = (const char*)pw + (size_t)cb * NKT * TILE_BYTES;

  GEMM_STAGE(smem, 0);
  GEMM_STAGE(smem + 16384, 1);

#pragma unroll 1
  for (int kt = 0; kt < 22; kt += 2) {
    KBODY(0, kt, 4, 1);
    KBODY(1, kt + 1, 4, 1);
  }
  KBODY(0, 22, 4, 0);
  KBODY(1, 23, 0, 0);

  // epilogue: stage relu(acc+b) f32 in LDS [32][132] (first 16.9KB);
  // scol at +17408; vectorized x-load + h-store + colsum.
  float* stage = (float*)smem;
  float* scol = (float*)(smem + 17408);
  const int SROW = 132;  // 528B rows: 16B-aligned, 2-way-max bank aliasing
  if (t < 128) scol[t] = 0.f;
  f32x4 cp = {0.f, 0.f, 0.f, 0.f};
  int jc = (t & 31) * 4;           // 4 consecutive cols per thread (fixed)
  int rsub = t >> 5;               // 0..7
  int colb0 = cb * 128;
  __syncthreads();
  for (int m = 0; m < 4; ++m) {
#pragma unroll
    for (int reg = 0; reg < 4; ++reg) {
      int lrow = wm * 16 + g * 4 + reg;
#pragma unroll
      for (int n = 0; n < 4; ++n)
        stage[lrow * SROW + wn * 64 + n * 16 + r16] = fmaxf(acc[m][n][reg] + bn[n], 0.f);
    }
    __syncthreads();
#pragma unroll
    for (int it = 0; it < 4; ++it) {
      int lrow = it * 8 + rsub;
      int row = bm * BM + (lrow >> 4) * 64 + m * 16 + (lrow & 15);
      if (row < N_NODES) {
        f32x4 v = *(const f32x4*)&stage[lrow * SROW + jc];
        f32x4 xv = *(const f32x4*)(x + (size_t)row * D_MODEL + colb0 + jc);
        v += xv;
        *(f32x4*)(hout + (size_t)row * D_MODEL + colb0 + jc) = v;
        cp += v;
      }
    }
    __syncthreads();
  }
#pragma unroll
  for (int c = 0; c < 4; ++c) atomicAdd(&scol[jc + c], cp[c]);
  __syncthreads();
  if (t < 128) atomicAdd(&colsum[cb * 128 + t], scol[t]);
}

// ---- final: out = (colsum/N) @ Wl + bl ----
__global__ void k_final(const float* __restrict__ colsum, const float* __restrict__ Wl,
                        const float* __restrict__ bl, float* __restrict__ out) {
  int j = blockIdx.x * 128 + threadIdx.x;
  if (j >= D_MODEL) return;
  float s = 0.f;
  for (int k = 0; k < D_MODEL; ++k)
    s += colsum[k] * Wl[(size_t)k * D_MODEL + j];
  out[j] = s * (1.0f / (float)N_NODES) + bl[j];
}

extern "C" void kernel_launch(void* const* d_in, const int* in_sizes, int n_in,
                              void* d_out, int out_size, void* d_ws, size_t ws_size,
                              hipStream_t stream) {
  const float* x      = (const float*)d_in[0];
  const unsigned* edg = (const unsigned*)d_in[1];
  const float* W1 = (const float*)d_in[2];
  const float* b1 = (const float*)d_in[3];
  const float* W2 = (const float*)d_in[4];
  const float* b2 = (const float*)d_in[5];
  const float* W3 = (const float*)d_in[6];
  const float* b3 = (const float*)d_in[7];
  const float* Wl = (const float*)d_in[8];
  const float* bl = (const float*)d_in[9];

  float* hout = (float*)d_out;
  float* oout = hout + (size_t)N_NODES * D_MODEL;

  char* ws = (char*)d_ws;
  size_t off = 0;
  ushort_t* t = (ushort_t*)(ws + off);   off += (size_t)N_NODES * D_MODEL * 2;  // 76.8 MB
  ushort_t* pagg = (ushort_t*)(ws + off); off += (size_t)M_PAD * D_MODEL * 2;   // 76.9 MB
  ushort_t* pw0 = (ushort_t*)(ws + off); off += (size_t)D_MODEL * D_MODEL * 2;
  ushort_t* pw1 = (ushort_t*)(ws + off); off += (size_t)D_MODEL * D_MODEL * 2;
  ushort_t* pw2 = (ushort_t*)(ws + off); off += (size_t)D_MODEL * D_MODEL * 2;
  float* dinv = (float*)(ws + off);      off += 50176 * 4;
  int* counts = (int*)(ws + off);        off += 50176 * 4;
  int* rowptr = (int*)(ws + off);        off += 50304 * 4;
  int* csr = (int*)(ws + off);           off += (size_t)N_EDGES * 4;
  int* bsum = (int*)(ws + off);          off += 256 * 4;
  int* boff = (int*)(ws + off);          off += 256 * 4;
  float* colsum = (float*)(ws + off);    off += 1024;
  int* eflag = (int*)(ws + off);         off += 256;

  // setup (edge structure is static across layers)
  k_init<<<196, 256, 0, stream>>>(edg, counts, colsum, eflag);
  k_count<<<391, 256, 0, stream>>>(edg, eflag, counts);
  k_scan1<<<196, 256, 0, stream>>>(counts, rowptr, bsum, dinv);
  k_scan2<<<1, 256, 0, stream>>>(bsum, boff);
  k_scan3<<<196, 256, 0, stream>>>(rowptr, boff, counts);
  k_fill<<<391, 256, 0, stream>>>(edg, eflag, rowptr, counts, csr);
  k_pack_w3<<<864, 256, 0, stream>>>(W1, W2, W3, pw0);

  const int NGB = N_NODES / GROWS0;  // 3125
  // layer 1 (gather fused with dinv*x scaling)
  k_gather_x<<<NGB, 256, 0, stream>>>(rowptr, csr, dinv, x, pagg);
  k_gemm12<<<NWG, 256, 0, stream>>>(pagg, pw0, dinv, b1, t);
  // layer 2
  k_gather_agg<<<NGB, 256, 0, stream>>>(rowptr, csr, dinv, t, pagg);
  k_gemm12<<<NWG, 256, 0, stream>>>(pagg, pw1, dinv, b2, t);
  // layer 3 (epilogue fuses bias+relu+residual+colsum, f32 out)
  k_gather_agg<<<NGB, 256, 0, stream>>>(rowptr, csr, dinv, t, pagg);
  k_gemm3<<<NWG, 256, 0, stream>>>(pagg, pw2, b3, x, hout, colsum);

  k_final<<<6, 128, 0, stream>>>(colsum, Wl, bl, oout);
}